// Round 13
// baseline (68.200 us; speedup 1.0000x reference)
//
#include <hip/hip_runtime.h>
#include <hip/hip_fp16.h>

// SSIM loss, v-FIRST packed-f16 sweep. Ring holds RAW rows (x, y, x^2+y^2:
// 33 half2 regs vs h-first's 55 -> fits arch VGPRs, no AGPR shuttle).
// Per output row: v-conv 4 maps from ring (no alignbits), exchange v-map
// words through wave-private LDS [map][64], h-conv via 7-word windows with
// funnel-shift odd-tap views, SSIM formula in f32 (needs only mu1, mu2,
// E[x^2+y^2], E[xy]). 5 overlapping 116-col strips per 512 cols; lanes 3-60
// produce valid outputs, edges masked. ZERO barriers, no raw-row LDS.

#define ROWS 32
#define NIT  (ROWS + 10)         // 42 staged rows per strip
#define NSTRIP 3840              // 48 img * 16 row-bands * 5 col-strips
#define NBLK  (NSTRIP / 4)       // 960 blocks
#define NPIX  12582912.0

static __device__ __forceinline__ unsigned fun16(unsigned hi, unsigned lo) {
    return (unsigned)((((unsigned long long)hi << 32) | lo) >> 16);  // v_alignbit
}
static __device__ __forceinline__ unsigned h2u(__half2 v) {
    unsigned u; __builtin_memcpy(&u, &v, 4); return u;
}
static __device__ __forceinline__ __half2 u2h(unsigned u) {
    __half2 v; __builtin_memcpy(&v, &u, 4); return v;
}

__global__ __launch_bounds__(256) void ssim_vfirst_kernel(
    const float* __restrict__ X, const float* __restrict__ Y,
    float* __restrict__ partial)
{
    // wave-private v-map exchange: [wave][map][word], 4096 B, stride-1 access
    __shared__ unsigned vb[4][4][64];

    const int tid  = threadIdx.x;
    const int lane = tid & 63;
    const int w    = tid >> 6;
    const int sid  = blockIdx.x * 4 + w;
    const int img  = sid / 80;           // 16 bands * 5 strips
    const int rem  = sid - img * 80;
    const int band = rem / 5;
    const int s    = rem - band * 5;
    const int r0   = band * ROWS;
    const int oc   = 116 * s - 6;        // col of word 0 (even)
    const int c2   = oc + 2 * lane;      // this thread's word col

    const float* __restrict__ Xi = X + (size_t)img * (512 * 512);
    const float* __restrict__ Yi = Y + (size_t)img * (512 * 512);

    // Gaussian weights (matches jnp construction)
    float g[11];
    {
        float sum = 0.f;
        #pragma unroll
        for (int i = 0; i < 11; ++i) {
            float d = (float)(i - 5);
            float e = expf(-d * d * (1.0f / 4.5f));
            g[i] = e; sum += e;
        }
        float inv = 1.0f / sum;
        #pragma unroll
        for (int i = 0; i < 11; ++i) g[i] *= inv;
    }
    __half2 w2[11];
    #pragma unroll
    for (int i = 0; i < 11; ++i) w2[i] = __float2half2_rn(g[i]);

    const bool  cok = ((unsigned)c2 < 512u);   // word fully in image (512 even)
    const float msk = (lane >= 3 && lane <= 60 && cok) ? 1.f : 0.f;
    const int   bw  = min(max(lane - 3, 0), 57);   // window base word (clamped)

    #define LOADROW(J)                                                       \
        {                                                                    \
            const int gr = r0 - 5 + (J);                                     \
            nx = make_float2(0.f, 0.f); ny = nx;                             \
            if ((unsigned)gr < 512u && cok) {                                \
                nx = *(const float2*)(Xi + (size_t)gr * 512 + c2);           \
                ny = *(const float2*)(Yi + (size_t)gr * 512 + c2);           \
            }                                                                \
        }

    // h-conv of one v-map from its 7-word window (odd taps direct, even via funnel)
    #define HPASS(OUT, D)                                                    \
        {                                                                    \
            __half2 xk = u2h(fun16(D[1], D[0]));                             \
            OUT = __hmul2(w2[0], xk);                                        \
            _Pragma("unroll")                                                \
            for (int k = 1; k < 11; ++k) {                                   \
                unsigned u;                                                  \
                if (k & 1) u = D[(k + 1) >> 1];                              \
                else       u = fun16(D[(k >> 1) + 1], D[k >> 1]);            \
                OUT = __hfma2(w2[k], u2h(u), OUT);                           \
            }                                                                \
        }

    float2 nx, ny;
    LOADROW(0);

    __half2 rx[11], ry[11], rss[11];   // raw ring — static indices only
    float acc = 0.f;
    const float C1 = 1e-4f, C2 = 9e-4f;

    #pragma unroll 1
    for (int jb = 0; jb < 44; jb += 11) {
        #pragma unroll
        for (int ph = 0; ph < 11; ++ph) {
            const int j = jb + ph;          // j % 11 == ph
            if (j < NIT) {
                // push row j into ring; form x^2+y^2 once per row
                {
                    const __half2 hx = __floats2half2_rn(nx.x, nx.y);
                    const __half2 hy = __floats2half2_rn(ny.x, ny.y);
                    rx[ph] = hx; ry[ph] = hy;
                    rss[ph] = __hfma2(hy, hy, __hmul2(hx, hx));
                }

                // prefetch next row (hides global latency under math)
                if (j + 1 < NIT) LOADROW(j + 1);

                if (j >= 10) {
                    // ---- v-conv: 4 maps from ring, 6 ops/tap ----
                    __half2 vx, vy, vss, vxy;
                    {
                        const int sl = (ph + 1) % 11;
                        const __half2 xk = rx[sl], yk = ry[sl];
                        const __half2 wx = __hmul2(w2[0], xk);
                        vx = wx; vy = __hmul2(w2[0], yk);
                        vss = __hmul2(w2[0], rss[sl]);
                        vxy = __hmul2(wx, yk);
                    }
                    #pragma unroll
                    for (int k = 1; k < 11; ++k) {
                        const int sl = (ph + 1 + k) % 11;
                        const __half2 xk = rx[sl], yk = ry[sl];
                        const __half2 wx = __hmul2(w2[k], xk);
                        vx  = __hadd2(vx, wx);
                        vy  = __hfma2(w2[k], yk, vy);
                        vss = __hfma2(w2[k], rss[sl], vss);
                        vxy = __hfma2(wx, yk, vxy);
                    }

                    // ---- exchange through wave-private LDS (in-order wave DS) ----
                    vb[w][0][lane] = h2u(vx);
                    vb[w][1][lane] = h2u(vy);
                    vb[w][2][lane] = h2u(vss);
                    vb[w][3][lane] = h2u(vxy);

                    unsigned D0[7], D1[7], D2[7], D3[7];
                    #pragma unroll
                    for (int k2 = 0; k2 < 7; ++k2) D0[k2] = vb[w][0][bw + k2];
                    #pragma unroll
                    for (int k2 = 0; k2 < 7; ++k2) D1[k2] = vb[w][1][bw + k2];
                    #pragma unroll
                    for (int k2 = 0; k2 < 7; ++k2) D2[k2] = vb[w][2][bw + k2];
                    #pragma unroll
                    for (int k2 = 0; k2 < 7; ++k2) D3[k2] = vb[w][3][bw + k2];

                    // ---- h-conv the 4 maps ----
                    __half2 hm1, hm2, hss, hxy;
                    HPASS(hm1, D0);
                    HPASS(hm2, D1);
                    HPASS(hss, D2);
                    HPASS(hxy, D3);

                    // ---- SSIM formula (f32), masked accumulate ----
                    const float2 m1 = __half22float2(hm1);
                    const float2 m2 = __half22float2(hm2);
                    const float2 ss = __half22float2(hss);
                    const float2 xy = __half22float2(hxy);
                    float val = 0.f;
                    #pragma unroll
                    for (int h = 0; h < 2; ++h) {
                        const float a1 = h ? m1.y : m1.x;
                        const float a2 = h ? m2.y : m2.x;
                        const float bs = h ? ss.y : ss.x;
                        const float bz = h ? xy.y : xy.x;
                        const float m11 = a1 * a1, m22 = a2 * a2, m12 = a1 * a2;
                        const float s12  = bz - m12;
                        const float ssum = bs - m11 - m22;
                        const float num = (2.f * m12 + C1) * (2.f * s12 + C2);
                        const float den = (m11 + m22 + C1) * (ssum + C2);
                        val = fmaf(num, __builtin_amdgcn_rcpf(den), val);
                    }
                    acc = fmaf(msk, val, acc);
                }
            }
        }
    }

    // wave reduction; each wave owns its strip's partial
    #pragma unroll
    for (int off = 32; off > 0; off >>= 1)
        acc += __shfl_down(acc, off, 64);
    if (lane == 0) partial[sid] = acc;
}

__global__ __launch_bounds__(256) void ssim_reduce_kernel(
    const float* __restrict__ partial, float* __restrict__ out)
{
    const int tid = threadIdx.x;
    double s = 0.0;
    for (int i = tid; i < NSTRIP; i += 256) s += (double)partial[i];
    __shared__ double sd[256];
    sd[tid] = s;
    __syncthreads();
    for (int off = 128; off > 0; off >>= 1) {
        if (tid < off) sd[tid] += sd[tid + off];
        __syncthreads();
    }
    if (tid == 0) out[0] = (float)(1.0 - sd[0] / NPIX);
}

extern "C" void kernel_launch(void* const* d_in, const int* in_sizes, int n_in,
                              void* d_out, int out_size, void* d_ws, size_t ws_size,
                              hipStream_t stream) {
    const float* X = (const float*)d_in[0];
    const float* Y = (const float*)d_in[1];
    float* partial = (float*)d_ws;   // NSTRIP floats = 15 KiB
    float* out = (float*)d_out;

    ssim_vfirst_kernel<<<NBLK, 256, 0, stream>>>(X, Y, partial);
    ssim_reduce_kernel<<<1, 256, 0, stream>>>(partial, out);
}

// Round 14
// 59.618 us; speedup vs baseline: 1.1440x; 1.1440x over previous
//
#include <hip/hip_runtime.h>
#include <hip/hip_fp16.h>

// SSIM loss, packed-f16 row-sweep, fully independent waves, ROWS=32.
// Round-14 A/B: fun16 funnel-shift now uses __builtin_amdgcn_alignbit
// (guaranteed single v_alignbit_b32; the 64-bit concat-shift form may
// lower as a multi-op 64-bit shift). Otherwise identical to round 11.
// Wave-private LDS double-buffered row staging (+3 halo words each side);
// h-pass from 7 consecutive dwords per map (stride-1, conflict-free) with
// alignbit odd-tap views; 5x11 half2 register ring; v-pass from ring;
// SSIM formula in f32. ZERO block barriers.

#define ROWS 32
#define NIT  (ROWS + 10)         // 42 staged rows per strip
#define NSTRIP 3072              // 48 img * 16 row-bands * 4 col-strips
#define NBLK  (NSTRIP / 4)       // 768 blocks
#define NPIX  12582912.0

static __device__ __forceinline__ unsigned fun16(unsigned hi, unsigned lo) {
    return __builtin_amdgcn_alignbit(hi, lo, 16);   // v_alignbit_b32
}
static __device__ __forceinline__ unsigned h2u(__half2 v) {
    unsigned u; __builtin_memcpy(&u, &v, 4); return u;
}
static __device__ __forceinline__ __half2 u2h(unsigned u) {
    __half2 v; __builtin_memcpy(&v, &u, 4); return v;
}

__global__ __launch_bounds__(256, 4) void ssim_sweep32_kernel(
    const float* __restrict__ X, const float* __restrict__ Y,
    float* __restrict__ partial)
{
    // [wave][map][dbuf][word]; word i = half2 (x[cs-6+2i], x[cs-5+2i]); 4608 B
    __shared__ unsigned sbw[4][2][2][72];

    const int tid  = threadIdx.x;
    const int lane = tid & 63;
    const int w    = tid >> 6;
    const int sid  = blockIdx.x * 4 + w;
    const int img  = sid >> 6;          // 16 bands * 4 strips = 64
    const int rb   = (sid >> 2) & 15;
    const int cs   = (sid & 3) << 7;    // strip col start
    const int r0   = rb * ROWS;

    const float* __restrict__ Xi = X + (size_t)img * (512 * 512);
    const float* __restrict__ Yi = Y + (size_t)img * (512 * 512);

    // Gaussian weights (matches jnp construction)
    float g[11];
    {
        float s = 0.f;
        #pragma unroll
        for (int i = 0; i < 11; ++i) {
            float d = (float)(i - 5);
            float e = expf(-d * d * (1.0f / 4.5f));
            g[i] = e; s += e;
        }
        float inv = 1.0f / s;
        #pragma unroll
        for (int i = 0; i < 11; ++i) g[i] *= inv;
    }
    __half2 w2[11];
    #pragma unroll
    for (int i = 0; i < 11; ++i) w2[i] = __float2half2_rn(g[i]);

    const int c2 = cs + 2 * lane;       // own 2 cols (always in-image)

    // halo duty: lanes 48-53 -> map0 words {0,1,2,67,68,69}; 56-61 -> map1
    int hq = -1, hm = 0;
    if (lane >= 48 && lane < 54)      { hq = lane - 48; hm = 0; }
    else if (lane >= 56 && lane < 62) { hq = lane - 56; hm = 1; }
    const int  hwd = (hq < 0) ? 0 : (hq < 3 ? hq : 64 + hq);
    const int  hc  = cs - 6 + 2 * hwd;
    const bool hok = (hq >= 0) && ((unsigned)hc < 512u);
    const float* hbase = hm ? Yi : Xi;

    float2 nvx, nvy, nvh;
    #define STAGE_LOAD(J)                                                    \
        {                                                                    \
            int gr = r0 - 5 + (J);                                           \
            nvx = make_float2(0.f, 0.f); nvy = nvx; nvh = nvx;               \
            if ((unsigned)gr < 512u) {                                       \
                const float* xr = Xi + (size_t)gr * 512;                     \
                const float* yr = Yi + (size_t)gr * 512;                     \
                nvx = *(const float2*)(xr + c2);                             \
                nvy = *(const float2*)(yr + c2);                             \
                if (hok) nvh = *(const float2*)(hbase + (size_t)gr * 512 + hc); \
            }                                                                \
        }
    #define STAGE_WRITE(BUF)                                                 \
        {                                                                    \
            sbw[w][0][BUF][3 + lane] = h2u(__floats2half2_rn(nvx.x, nvx.y)); \
            sbw[w][1][BUF][3 + lane] = h2u(__floats2half2_rn(nvy.x, nvy.y)); \
            if (hq >= 0) sbw[w][hm][BUF][hwd] = h2u(__floats2half2_rn(nvh.x, nvh.y)); \
        }

    // prologue: stage row 0 into buf 0
    STAGE_LOAD(0);
    STAGE_WRITE(0);

    __half2 ring[5][11];     // x, y, xx, yy, xy — static indices only
    float acc = 0.f;
    const float C1 = 1e-4f, C2 = 9e-4f;
    const __half2 hz = __float2half2_rn(0.f);

    #pragma unroll 1
    for (int jb = 0; jb < 44; jb += 11) {
        #pragma unroll
        for (int ph = 0; ph < 11; ++ph) {
            const int j = jb + ph;          // j % 11 == ph
            if (j < NIT) {
                const int cur = j & 1, nxt = cur ^ 1;

                // issue next-row global loads early (hide latency)
                if (j + 1 < NIT) STAGE_LOAD(j + 1);

                // read 7-word windows (stride-1, conflict-free)
                unsigned Dx[7], Dy[7];
                #pragma unroll
                for (int k2 = 0; k2 < 7; ++k2) Dx[k2] = sbw[w][0][cur][lane + k2];
                #pragma unroll
                for (int k2 = 0; k2 < 7; ++k2) Dy[k2] = sbw[w][1][cur][lane + k2];

                // h-pass: 11 taps; odd k -> direct word, even k -> alignbit view
                __half2 hx, hy, hxx, hyy, hxy;
                {   // k = 0 initializes (saves the zero-add)
                    const __half2 xk = u2h(fun16(Dx[1], Dx[0]));
                    const __half2 yk = u2h(fun16(Dy[1], Dy[0]));
                    const __half2 wx = __hmul2(w2[0], xk);
                    const __half2 wy = __hmul2(w2[0], yk);
                    hx = wx; hy = wy;
                    hxx = __hmul2(wx, xk);
                    hyy = __hmul2(wy, yk);
                    hxy = __hmul2(wx, yk);
                }
                #pragma unroll
                for (int k = 1; k < 11; ++k) {
                    unsigned ux, uy;
                    if (k & 1) { ux = Dx[(k + 1) >> 1];            uy = Dy[(k + 1) >> 1]; }
                    else       { ux = fun16(Dx[(k >> 1) + 1], Dx[k >> 1]);
                                 uy = fun16(Dy[(k >> 1) + 1], Dy[k >> 1]); }
                    const __half2 xk = u2h(ux), yk = u2h(uy);
                    const __half2 wx = __hmul2(w2[k], xk);
                    const __half2 wy = __hmul2(w2[k], yk);
                    hx  = __hadd2(hx, wx);
                    hy  = __hadd2(hy, wy);
                    hxx = __hfma2(wx, xk, hxx);
                    hyy = __hfma2(wy, yk, hyy);
                    hxy = __hfma2(wx, yk, hxy);
                }
                ring[0][ph] = hx;  ring[1][ph] = hy;
                ring[2][ph] = hxx; ring[3][ph] = hyy; ring[4][ph] = hxy;

                // v-pass from ring (valid once j >= 10)
                if (j >= 10) {
                    __half2 mu1 = hz, mu2 = hz, vxx = hz, vyy = hz, vxy = hz;
                    #pragma unroll
                    for (int k = 0; k < 11; ++k) {
                        const int s = (ph + 1 + k) % 11;
                        mu1 = __hfma2(w2[k], ring[0][s], mu1);
                        mu2 = __hfma2(w2[k], ring[1][s], mu2);
                        vxx = __hfma2(w2[k], ring[2][s], vxx);
                        vyy = __hfma2(w2[k], ring[3][s], vyy);
                        vxy = __hfma2(w2[k], ring[4][s], vxy);
                    }
                    const float2 m1 = __half22float2(mu1);
                    const float2 m2 = __half22float2(mu2);
                    const float2 xx = __half22float2(vxx);
                    const float2 yy = __half22float2(vyy);
                    const float2 xy = __half22float2(vxy);
                    #pragma unroll
                    for (int h = 0; h < 2; ++h) {
                        const float a1 = h ? m1.y : m1.x;
                        const float a2 = h ? m2.y : m2.x;
                        const float bx = h ? xx.y : xx.x;
                        const float by = h ? yy.y : yy.x;
                        const float bz = h ? xy.y : xy.x;
                        const float m11 = a1 * a1, m22 = a2 * a2, m12 = a1 * a2;
                        const float s1 = bx - m11, s2 = by - m22, s12 = bz - m12;
                        const float num = (2.f * m12 + C1) * (2.f * s12 + C2);
                        const float den = (m11 + m22 + C1) * (s1 + s2 + C2);
                        acc = fmaf(num, __builtin_amdgcn_rcpf(den), acc);
                    }
                }

                // write next row into the other buffer (wave-private, no
                // barrier; DS ops are wave-in-order, compiler adds dep waits)
                if (j + 1 < NIT) STAGE_WRITE(nxt);
            }
        }
    }

    // wave reduction; each wave owns its strip's partial
    #pragma unroll
    for (int off = 32; off > 0; off >>= 1)
        acc += __shfl_down(acc, off, 64);
    if (lane == 0) partial[sid] = acc;
}

__global__ __launch_bounds__(256) void ssim_reduce_kernel(
    const float* __restrict__ partial, float* __restrict__ out)
{
    const int tid = threadIdx.x;
    double s = 0.0;
    for (int i = tid; i < NSTRIP; i += 256) s += (double)partial[i];
    __shared__ double sd[256];
    sd[tid] = s;
    __syncthreads();
    for (int off = 128; off > 0; off >>= 1) {
        if (tid < off) sd[tid] += sd[tid + off];
        __syncthreads();
    }
    if (tid == 0) out[0] = (float)(1.0 - sd[0] / NPIX);
}

extern "C" void kernel_launch(void* const* d_in, const int* in_sizes, int n_in,
                              void* d_out, int out_size, void* d_ws, size_t ws_size,
                              hipStream_t stream) {
    const float* X = (const float*)d_in[0];
    const float* Y = (const float*)d_in[1];
    float* partial = (float*)d_ws;   // NSTRIP floats = 12 KiB
    float* out = (float*)d_out;

    ssim_sweep32_kernel<<<NBLK, 256, 0, stream>>>(X, Y, partial);
    ssim_reduce_kernel<<<1, 256, 0, stream>>>(partial, out);
}